// Round 2
// baseline (1548.699 us; speedup 1.0000x reference)
//
#include <hip/hip_runtime.h>

#define NN 100000
#define NE 800000
#define NL 200000
#define HEADS 4

// ---------------- small-N row GEMM (kept for ncols==32) ---------------------
template<int K, int TPB, int RPB, bool RELU, bool BIAS>
__launch_bounds__(TPB)
__global__ void gemm_rows(const float* __restrict__ A, const float* __restrict__ B,
                          const float* __restrict__ bias, float* __restrict__ C,
                          int n_rows, int ncols) {
    __shared__ float As[RPB][K];
    const int row0 = blockIdx.x * RPB;
    for (int i = threadIdx.x; i < RPB * K; i += TPB) {
        int r = i / K, k = i % K;
        int gr = row0 + r;
        As[r][k] = (gr < n_rows) ? A[(size_t)gr * K + k] : 0.f;
    }
    __syncthreads();
    const int cpr = TPB / RPB;
    const int r   = threadIdx.x / cpr;
    const int j0  = threadIdx.x % cpr;
    const int gr  = row0 + r;
    if (gr >= n_rows) return;
    for (int j = j0; j < ncols; j += cpr) {
        float s = BIAS ? bias[j] : 0.f;
        #pragma unroll
        for (int k = 0; k < K; ++k) s += As[r][k] * B[k * ncols + j];
        if (RELU) s = fmaxf(s, 0.f);
        C[(size_t)gr * ncols + j] = s;
    }
}

// ---------------- mid tile GEMM (BM=64, BN=64, 256 thr) — used for d2 -------
template<int K, int BN, bool RELU, bool BIAS>
__launch_bounds__(256, 4)
__global__ void gemm_tiled(const float* __restrict__ A, const float* __restrict__ B,
                           const float* __restrict__ bias, float* __restrict__ C,
                           int M, int N) {
    constexpr int BM = 64, BK = 32;
    constexpr int TN = BN / 16;
    __shared__ float As[BK][BM];
    __shared__ float Bs[BK][BN];
    const int tid  = threadIdx.x;
    const int row0 = blockIdx.x * BM;
    const int col0 = blockIdx.y * BN;
    const int ty   = tid >> 4;
    const int tx   = tid & 15;

    float acc[4][TN] = {};

    for (int k0 = 0; k0 < K; k0 += BK) {
        for (int i = tid * 4; i < BM * BK; i += 1024) {
            int r  = i >> 5;
            int kk = i & 31;
            int gr = row0 + r;
            float4 v = make_float4(0.f, 0.f, 0.f, 0.f);
            if (gr < M) v = *(const float4*)(A + (size_t)gr * K + k0 + kk);
            int sw = ((kk >> 2) & 3) << 3;
            As[kk + 0][r ^ sw] = v.x;
            As[kk + 1][r ^ sw] = v.y;
            As[kk + 2][r ^ sw] = v.z;
            As[kk + 3][r ^ sw] = v.w;
        }
        for (int i = tid * 4; i < BK * BN; i += 1024) {
            int kk = i / BN, c = i % BN;
            int gc = col0 + c;
            float4 v = make_float4(0.f, 0.f, 0.f, 0.f);
            if (gc < N) v = *(const float4*)(B + (size_t)(k0 + kk) * N + gc);
            *(float4*)&Bs[kk][c] = v;
        }
        __syncthreads();
        #pragma unroll
        for (int kk = 0; kk < BK; ++kk) {
            int sw = ((kk >> 2) & 3) << 3;
            float4 a = *(const float4*)&As[kk][(ty * 4) ^ sw];
            float av[4] = {a.x, a.y, a.z, a.w};
            float bv[TN];
            #pragma unroll
            for (int q = 0; q < TN / 4; ++q) {
                float4 b = *(const float4*)&Bs[kk][q * 64 + tx * 4];
                bv[q*4+0] = b.x; bv[q*4+1] = b.y; bv[q*4+2] = b.z; bv[q*4+3] = b.w;
            }
            #pragma unroll
            for (int i = 0; i < 4; ++i)
                #pragma unroll
                for (int j = 0; j < TN; ++j)
                    acc[i][j] = fmaf(av[i], bv[j], acc[i][j]);
        }
        __syncthreads();
    }

    #pragma unroll
    for (int i = 0; i < 4; ++i) {
        int gr = row0 + ty * 4 + i;
        if (gr >= M) continue;
        #pragma unroll
        for (int q = 0; q < TN / 4; ++q) {
            int gc = col0 + q * 64 + tx * 4;
            if (gc >= N) continue;
            float4 o = make_float4(acc[i][q*4], acc[i][q*4+1], acc[i][q*4+2], acc[i][q*4+3]);
            if (BIAS) { o.x += bias[gc]; o.y += bias[gc+1]; o.z += bias[gc+2]; o.w += bias[gc+3]; }
            if (RELU) { o.x = fmaxf(o.x,0.f); o.y = fmaxf(o.y,0.f); o.z = fmaxf(o.z,0.f); o.w = fmaxf(o.w,0.f); }
            *(float4*)(C + (size_t)gr * N + gc) = o;
        }
    }
}

// ---------------- big tile GEMM (BM=128, BN=128/256, 512 thr) ---------------
// Thread (ty=tid/16 in 0..31, tx=tid%16) owns a 4 x TN register tile.
// A staged transposed in LDS with XOR swizzle (conflict-free write & read).
template<int K, int BN, bool RELU, bool BIAS>
__launch_bounds__(512, 4)
__global__ void gemm_tiled2(const float* __restrict__ A, const float* __restrict__ B,
                            const float* __restrict__ bias, float* __restrict__ C,
                            int M, int N) {
    constexpr int BM = 128, BK = 32;
    constexpr int TN = BN / 16;      // 8 or 16
    __shared__ float As[BK][BM];
    __shared__ float Bs[BK][BN];
    const int tid  = threadIdx.x;
    const int row0 = blockIdx.x * BM;
    const int col0 = blockIdx.y * BN;
    const int ty   = tid >> 4;       // 0..31
    const int tx   = tid & 15;

    float acc[4][TN] = {};

    #pragma unroll 1
    for (int k0 = 0; k0 < K; k0 += BK) {
        // stage A chunk (BM*BK = 4096 floats): coalesced loads, swizzled transposed stores
        #pragma unroll
        for (int i0 = 0; i0 < BM * BK; i0 += 2048) {
            int i  = i0 + tid * 4;
            int r  = i >> 5;
            int kk = i & 31;
            int gr = row0 + r;
            float4 v = make_float4(0.f, 0.f, 0.f, 0.f);
            if (gr < M) v = *(const float4*)(A + (size_t)gr * K + k0 + kk);
            int sw = ((kk >> 2) & 3) << 3;
            As[kk + 0][r ^ sw] = v.x;
            As[kk + 1][r ^ sw] = v.y;
            As[kk + 2][r ^ sw] = v.z;
            As[kk + 3][r ^ sw] = v.w;
        }
        // stage B chunk (BK*BN floats): coalesced float4
        #pragma unroll
        for (int i0 = 0; i0 < BK * BN; i0 += 2048) {
            int i  = i0 + tid * 4;
            int kk = i / BN, c = i % BN;
            int gc = col0 + c;
            float4 v = make_float4(0.f, 0.f, 0.f, 0.f);
            if (gc < N) v = *(const float4*)(B + (size_t)(k0 + kk) * N + gc);
            *(float4*)&Bs[kk][c] = v;
        }
        __syncthreads();

        #pragma unroll
        for (int kk = 0; kk < BK; ++kk) {
            int sw = ((kk >> 2) & 3) << 3;
            float4 a = *(const float4*)&As[kk][(ty * 4) ^ sw];
            float av[4] = {a.x, a.y, a.z, a.w};
            float bv[TN];
            #pragma unroll
            for (int q = 0; q < TN / 4; ++q) {
                float4 b = *(const float4*)&Bs[kk][q * 64 + tx * 4];
                bv[q*4+0] = b.x; bv[q*4+1] = b.y; bv[q*4+2] = b.z; bv[q*4+3] = b.w;
            }
            #pragma unroll
            for (int i = 0; i < 4; ++i)
                #pragma unroll
                for (int j = 0; j < TN; ++j)
                    acc[i][j] = fmaf(av[i], bv[j], acc[i][j]);
        }
        __syncthreads();
    }

    #pragma unroll
    for (int i = 0; i < 4; ++i) {
        int gr = row0 + ty * 4 + i;
        if (gr >= M) continue;
        #pragma unroll
        for (int q = 0; q < TN / 4; ++q) {
            int gc = col0 + q * 64 + tx * 4;
            if (gc >= N) continue;
            float4 o = make_float4(acc[i][q*4], acc[i][q*4+1], acc[i][q*4+2], acc[i][q*4+3]);
            if (BIAS) { o.x += bias[gc]; o.y += bias[gc+1]; o.z += bias[gc+2]; o.w += bias[gc+3]; }
            if (RELU) { o.x = fmaxf(o.x,0.f); o.y = fmaxf(o.y,0.f); o.z = fmaxf(o.z,0.f); o.w = fmaxf(o.w,0.f); }
            *(float4*)(C + (size_t)gr * N + gc) = o;
        }
    }
}

// ---------------- per-(node,head) attention logits --------------------------
template<int C>
__global__ void calc_alpha(const float* __restrict__ h, const float* __restrict__ a_src,
                           const float* __restrict__ a_dst, float* __restrict__ as_out,
                           float* __restrict__ ad_out) {
    int i = blockIdx.x * blockDim.x + threadIdx.x;   // n*HEADS + hd
    if (i >= NN * HEADS) return;
    int n = i / HEADS, hd = i % HEADS;
    const float* hp  = h + (size_t)n * HEADS * C + hd * C;
    const float* asp = a_src + hd * C;
    const float* adp = a_dst + hd * C;
    float s1 = 0.f, s2 = 0.f;
    #pragma unroll 8
    for (int c = 0; c < C; ++c) { float v = hp[c]; s1 += v * asp[c]; s2 += v * adp[c]; }
    as_out[i] = s1; ad_out[i] = s2;
}

__device__ __forceinline__ float lrelu02(float v) { return v > 0.f ? v : 0.2f * v; }

// ---------------- softmax numerator + denominator per (dst, head) -----------
// Also stores exp(e) per (edge, head) for reuse in aggregation.
__global__ void edge_denom(const int* __restrict__ src, const int* __restrict__ dst,
                           const float* __restrict__ as_, const float* __restrict__ ad_,
                           float* __restrict__ den, float* __restrict__ exb) {
    int i = blockIdx.x * blockDim.x + threadIdx.x;   // e*HEADS + hd
    if (i >= NE * HEADS) return;
    int e = i / HEADS, hd = i % HEADS;
    int s = src[e], d = dst[e];
    float v = lrelu02(as_[s * HEADS + hd] + ad_[d * HEADS + hd]);
    float ex = __expf(v);
    exb[i] = ex;
    atomicAdd(&den[d * HEADS + hd], ex);
}

// ---------------- normalize: exb <- exb / (den[dst]+eps) --------------------
__global__ void edge_weight(const int* __restrict__ dst, const float* __restrict__ den,
                            float* __restrict__ exb) {
    int i = blockIdx.x * blockDim.x + threadIdx.x;   // e*HEADS + hd
    if (i >= NE * HEADS) return;
    int e = i >> 2, hd = i & 3;
    int d = dst[e];
    exb[i] = exb[i] / (den[d * HEADS + hd] + 1e-16f);
}

// ---------------- weighted aggregation, heads folded ------------------------
template<int C>
__global__ void edge_agg(const int* __restrict__ src, const int* __restrict__ dst,
                         const float* __restrict__ wb, const float* __restrict__ h,
                         float* __restrict__ agg) {
    int tid = blockIdx.x * blockDim.x + threadIdx.x;
    int e = tid / C, c = tid % C;
    if (e >= NE) return;
    int s = src[e], d = dst[e];
    float sum = 0.f;
    #pragma unroll
    for (int hd = 0; hd < HEADS; ++hd)
        sum += wb[e * HEADS + hd] * h[(size_t)s * HEADS * C + hd * C + c];
    atomicAdd(&agg[(size_t)d * C + c], sum);
}

// ---------------- mean over heads + bias + relu ------------------------------
template<int C>
__global__ void finalize(const float* __restrict__ agg, const float* __restrict__ bias,
                         float* __restrict__ out) {
    int i = blockIdx.x * blockDim.x + threadIdx.x;   // n*C + c
    if (i >= NN * C) return;
    out[i] = fmaxf(agg[i] * 0.25f + bias[i % C], 0.f);
}

// ---------------- link decoder ----------------------------------------------
__global__ void link_kernel(const int* __restrict__ lsrc, const int* __restrict__ ldst,
                            const float* __restrict__ z, float* __restrict__ out) {
    int e = blockIdx.x * blockDim.x + threadIdx.x;
    if (e >= NL) return;
    const float4* zs = (const float4*)(z + (size_t)lsrc[e] * 32);
    const float4* zd = (const float4*)(z + (size_t)ldst[e] * 32);
    float sum = 0.f;
    #pragma unroll
    for (int i = 0; i < 8; ++i) {
        float4 a = zs[i], b = zd[i];
        sum += a.x * b.x + a.y * b.y + a.z * b.z + a.w * b.w;
    }
    out[e] = sum;
}

extern "C" void kernel_launch(void* const* d_in, const int* in_sizes, int n_in,
                              void* d_out, int out_size, void* d_ws, size_t ws_size,
                              hipStream_t stream) {
    const float* x     = (const float*)d_in[0];
    const int*   ei    = (const int*)d_in[1];
    const int*   eli   = (const int*)d_in[2];
    const float* W0    = (const float*)d_in[3];
    const float* as0   = (const float*)d_in[4];
    const float* ad0   = (const float*)d_in[5];
    const float* b0    = (const float*)d_in[6];
    const float* W1    = (const float*)d_in[7];
    const float* as1   = (const float*)d_in[8];
    const float* ad1   = (const float*)d_in[9];
    const float* b1    = (const float*)d_in[10];
    const float* lin_w = (const float*)d_in[11];
    const float* lin_b = (const float*)d_in[12];
    const float* d1_w  = (const float*)d_in[13];
    const float* d1_b  = (const float*)d_in[14];
    const float* d2_w  = (const float*)d_in[15];
    const float* d2_b  = (const float*)d_in[16];
    const float* d3_w  = (const float*)d_in[17];
    const float* d3_b  = (const float*)d_in[18];
    const float* d4_w  = (const float*)d_in[19];
    const float* d4_b  = (const float*)d_in[20];

    const int* src = ei;            // edge_index[0]
    const int* dst = ei + NE;       // edge_index[1]
    const int* ls  = eli;
    const int* ld  = eli + NL;

    float* ws = (float*)d_ws;
    // layout (floats): h [N*256] | agg [N*64] | out0/out1 [N*64] | as [N*4] | ad [N*4] | den [N*4] | exb [E*4]
    float* h_buf = ws;
    float* agg   = ws + (size_t)NN * 256;
    float* outb  = ws + (size_t)NN * 320;
    float* asb   = ws + (size_t)NN * 384;
    float* adb   = ws + (size_t)NN * 388;
    float* den   = ws + (size_t)NN * 392;
    float* exb   = ws + (size_t)NN * 396;    // [E, HEADS]
    // decoder intermediates reuse the h region
    float* z  = h_buf;                       // [N,32]
    float* e1 = h_buf + (size_t)NN * 32;     // [N,32]
    float* e2 = h_buf + (size_t)NN * 64;     // [N,64]
    float* e3 = h_buf + (size_t)NN * 128;    // [N,96]

    float* link_out = (float*)d_out;
    float* expr_out = (float*)d_out + NL;

    const int GM  = (NN + 63) / 64;          // 64-row tiles
    const int GM2 = (NN + 127) / 128;        // 128-row tiles

    // ---------------- Layer 0 (C=64 per head) ----------------
    gemm_tiled2<64, 256, false, false><<<dim3(GM2, 1), 512, 0, stream>>>(x, W0, nullptr, h_buf, NN, 256);
    calc_alpha<64><<<(NN * HEADS + 255) / 256, 256, 0, stream>>>(h_buf, as0, ad0, asb, adb);
    hipMemsetAsync(den, 0, (size_t)NN * HEADS * 4, stream);
    edge_denom<<<(NE * HEADS + 255) / 256, 256, 0, stream>>>(src, dst, asb, adb, den, exb);
    edge_weight<<<(NE * HEADS + 255) / 256, 256, 0, stream>>>(dst, den, exb);
    hipMemsetAsync(agg, 0, (size_t)NN * 64 * 4, stream);
    edge_agg<64><<<(size_t)(NE * 64) / 256, 256, 0, stream>>>(src, dst, exb, h_buf, agg);
    finalize<64><<<(NN * 64) / 256, 256, 0, stream>>>(agg, b0, outb);

    // ---------------- Layer 1 (C=32 per head) ----------------
    gemm_tiled2<64, 128, false, false><<<dim3(GM2, 1), 512, 0, stream>>>(outb, W1, nullptr, h_buf, NN, 128);
    calc_alpha<32><<<(NN * HEADS + 255) / 256, 256, 0, stream>>>(h_buf, as1, ad1, asb, adb);
    hipMemsetAsync(den, 0, (size_t)NN * HEADS * 4, stream);
    edge_denom<<<(NE * HEADS + 255) / 256, 256, 0, stream>>>(src, dst, asb, adb, den, exb);
    edge_weight<<<(NE * HEADS + 255) / 256, 256, 0, stream>>>(dst, den, exb);
    hipMemsetAsync(agg, 0, (size_t)NN * 32 * 4, stream);
    edge_agg<32><<<(size_t)(NE * 32) / 256, 256, 0, stream>>>(src, dst, exb, h_buf, agg);
    finalize<32><<<(NN * 32) / 256, 256, 0, stream>>>(agg, b1, outb);

    // ---------------- lin: z = out1 @ lin_w + lin_b ----------------
    gemm_rows<32, 256, 8, false, true><<<NN / 8, 256, 0, stream>>>(outb, lin_w, lin_b, z, NN, 32);

    // ---------------- link decoder ----------------
    link_kernel<<<(NL + 255) / 256, 256, 0, stream>>>(ls, ld, z, link_out);

    // ---------------- expression decoder ----------------
    gemm_rows<32, 256, 8, true, true><<<NN / 8, 256, 0, stream>>>(z, d1_w, d1_b, e1, NN, 32);
    gemm_tiled<32, 64,  true,  true><<<dim3(GM, 1), 256, 0, stream>>>(e1, d2_w, d2_b, e2, NN, 64);
    gemm_tiled2<64, 128, true,  true><<<dim3(GM2, 1), 512, 0, stream>>>(e2, d3_w, d3_b, e3, NN, 96);
    gemm_tiled2<96, 256, false, true><<<dim3(GM2, 2), 512, 0, stream>>>(e3, d4_w, d4_b, expr_out, NN, 500);
}

// Round 4
// 1340.715 us; speedup vs baseline: 1.1551x; 1.1551x over previous
//
#include <hip/hip_runtime.h>

#define NN 100000
#define NE 800000
#define NL 200000
#define HEADS 4

// ---------------- small-N row GEMM (ncols==32) ------------------------------
template<int K, int TPB, int RPB, bool RELU, bool BIAS>
__launch_bounds__(TPB)
__global__ void gemm_rows(const float* __restrict__ A, const float* __restrict__ B,
                          const float* __restrict__ bias, float* __restrict__ C,
                          int n_rows, int ncols) {
    __shared__ float As[RPB][K];
    const int row0 = blockIdx.x * RPB;
    for (int i = threadIdx.x; i < RPB * K; i += TPB) {
        int r = i / K, k = i % K;
        int gr = row0 + r;
        As[r][k] = (gr < n_rows) ? A[(size_t)gr * K + k] : 0.f;
    }
    __syncthreads();
    const int cpr = TPB / RPB;
    const int r   = threadIdx.x / cpr;
    const int j0  = threadIdx.x % cpr;
    const int gr  = row0 + r;
    if (gr >= n_rows) return;
    for (int j = j0; j < ncols; j += cpr) {
        float s = BIAS ? bias[j] : 0.f;
        #pragma unroll
        for (int k = 0; k < K; ++k) s += As[r][k] * B[k * ncols + j];
        if (RELU) s = fmaxf(s, 0.f);
        C[(size_t)gr * ncols + j] = s;
    }
}

// ---------------- tiled register-blocked GEMM (round-1 config) --------------
template<int K, int BN, bool RELU, bool BIAS>
__launch_bounds__(256, 4)
__global__ void gemm_tiled(const float* __restrict__ A, const float* __restrict__ B,
                           const float* __restrict__ bias, float* __restrict__ C,
                           int M, int N) {
    constexpr int BM = 64, BK = 32;
    constexpr int TN = BN / 16;
    __shared__ float As[BK][BM];
    __shared__ float Bs[BK][BN];
    const int tid  = threadIdx.x;
    const int row0 = blockIdx.x * BM;
    const int col0 = blockIdx.y * BN;
    const int ty   = tid >> 4;
    const int tx   = tid & 15;

    float acc[4][TN] = {};

    for (int k0 = 0; k0 < K; k0 += BK) {
        for (int i = tid * 4; i < BM * BK; i += 1024) {
            int r  = i >> 5;
            int kk = i & 31;
            int gr = row0 + r;
            float4 v = make_float4(0.f, 0.f, 0.f, 0.f);
            if (gr < M) v = *(const float4*)(A + (size_t)gr * K + k0 + kk);
            int sw = ((kk >> 2) & 3) << 3;
            As[kk + 0][r ^ sw] = v.x;
            As[kk + 1][r ^ sw] = v.y;
            As[kk + 2][r ^ sw] = v.z;
            As[kk + 3][r ^ sw] = v.w;
        }
        for (int i = tid * 4; i < BK * BN; i += 1024) {
            int kk = i / BN, c = i % BN;
            int gc = col0 + c;
            float4 v = make_float4(0.f, 0.f, 0.f, 0.f);
            if (gc < N) v = *(const float4*)(B + (size_t)(k0 + kk) * N + gc);
            *(float4*)&Bs[kk][c] = v;
        }
        __syncthreads();
        #pragma unroll
        for (int kk = 0; kk < BK; ++kk) {
            int sw = ((kk >> 2) & 3) << 3;
            float4 a = *(const float4*)&As[kk][(ty * 4) ^ sw];
            float av[4] = {a.x, a.y, a.z, a.w};
            float bv[TN];
            #pragma unroll
            for (int q = 0; q < TN / 4; ++q) {
                float4 b = *(const float4*)&Bs[kk][q * 64 + tx * 4];
                bv[q*4+0] = b.x; bv[q*4+1] = b.y; bv[q*4+2] = b.z; bv[q*4+3] = b.w;
            }
            #pragma unroll
            for (int i = 0; i < 4; ++i)
                #pragma unroll
                for (int j = 0; j < TN; ++j)
                    acc[i][j] = fmaf(av[i], bv[j], acc[i][j]);
        }
        __syncthreads();
    }

    #pragma unroll
    for (int i = 0; i < 4; ++i) {
        int gr = row0 + ty * 4 + i;
        if (gr >= M) continue;
        #pragma unroll
        for (int q = 0; q < TN / 4; ++q) {
            int gc = col0 + q * 64 + tx * 4;
            if (gc >= N) continue;
            float4 o = make_float4(acc[i][q*4], acc[i][q*4+1], acc[i][q*4+2], acc[i][q*4+3]);
            if (BIAS) { o.x += bias[gc]; o.y += bias[gc+1]; o.z += bias[gc+2]; o.w += bias[gc+3]; }
            if (RELU) { o.x = fmaxf(o.x,0.f); o.y = fmaxf(o.y,0.f); o.z = fmaxf(o.z,0.f); o.w = fmaxf(o.w,0.f); }
            *(float4*)(C + (size_t)gr * N + gc) = o;
        }
    }
}

// ---------------- per-(node,head) attention logits --------------------------
template<int C>
__global__ void calc_alpha(const float* __restrict__ h, const float* __restrict__ a_src,
                           const float* __restrict__ a_dst, float* __restrict__ as_out,
                           float* __restrict__ ad_out) {
    int i = blockIdx.x * blockDim.x + threadIdx.x;   // n*HEADS + hd
    if (i >= NN * HEADS) return;
    int n = i / HEADS, hd = i % HEADS;
    const float* hp  = h + (size_t)n * HEADS * C + hd * C;
    const float* asp = a_src + hd * C;
    const float* adp = a_dst + hd * C;
    float s1 = 0.f, s2 = 0.f;
    #pragma unroll 8
    for (int c = 0; c < C; ++c) { float v = hp[c]; s1 += v * asp[c]; s2 += v * adp[c]; }
    as_out[i] = s1; ad_out[i] = s2;
}

__device__ __forceinline__ float lrelu02(float v) { return v > 0.f ? v : 0.2f * v; }

// ---------------- CSR construction (dst-major), built once per launch -------
__global__ void deg_hist(const int* __restrict__ dst, int* __restrict__ deg) {
    int e = blockIdx.x * blockDim.x + threadIdx.x;
    if (e < NE) atomicAdd(&deg[dst[e]], 1);
}

// block-local exclusive scan of deg; per-block totals to bsum
__global__ void scan1(const int* __restrict__ deg, int* __restrict__ rs, int* __restrict__ bsum) {
    __shared__ int sd[256];
    int i = blockIdx.x * 256 + threadIdx.x;
    int v = (i < NN) ? deg[i] : 0;
    sd[threadIdx.x] = v;
    __syncthreads();
    for (int off = 1; off < 256; off <<= 1) {
        int t = (threadIdx.x >= off) ? sd[threadIdx.x - off] : 0;
        __syncthreads();
        sd[threadIdx.x] += t;
        __syncthreads();
    }
    if (i < NN) rs[i] = sd[threadIdx.x] - v;          // block-local exclusive
    if (threadIdx.x == 255) bsum[blockIdx.x] = sd[255];
}

// exclusive scan of the (<=512) block totals, in place
__global__ void scan2(int* __restrict__ bsum, int n) {
    __shared__ int sd[512];
    int v = (threadIdx.x < n) ? bsum[threadIdx.x] : 0;
    sd[threadIdx.x] = v;
    __syncthreads();
    for (int off = 1; off < 512; off <<= 1) {
        int t = (threadIdx.x >= off) ? sd[threadIdx.x - off] : 0;
        __syncthreads();
        sd[threadIdx.x] += t;
        __syncthreads();
    }
    if (threadIdx.x < n) bsum[threadIdx.x] = sd[threadIdx.x] - v;
}

__global__ void scan3(int* __restrict__ rs, int* __restrict__ cursor, const int* __restrict__ bsum) {
    int i = blockIdx.x * 256 + threadIdx.x;
    if (i < NN) {
        int v = rs[i] + bsum[blockIdx.x];
        rs[i] = v;
        cursor[i] = v;
    }
    if (i == 0) rs[NN] = NE;
}

__global__ void csr_scatter(const int* __restrict__ src, const int* __restrict__ dst,
                            int* __restrict__ cursor, int* __restrict__ csr_src) {
    int e = blockIdx.x * blockDim.x + threadIdx.x;
    if (e < NE) {
        int pos = atomicAdd(&cursor[dst[e]], 1);
        csr_src[pos] = src[e];
    }
}

// ---------------- fused per-node softmax + aggregation + finalize -----------
// C lanes per node: hd = l/(C/4), c4 = (l%(C/4))*4. Pass 1: denom (no atomics).
// Pass 2: gather h[s] as float4/lane, weight, accumulate. Head-reduce by
// shfl_xor, write relu(mean*0.25 + bias) once. No atomics anywhere.
template<int C>
__launch_bounds__(256)
__global__ void csr_agg(const int* __restrict__ row_start, const int* __restrict__ csr_src,
                        const float* __restrict__ as_, const float* __restrict__ ad_,
                        const float* __restrict__ h, const float* __restrict__ bias,
                        float* __restrict__ out) {
    constexpr int NPB = 256 / C;          // nodes per block
    const int tid = threadIdx.x;
    const int grp = tid / C;
    const int l   = tid % C;
    const int hd  = l / (C / 4);
    const int c4  = (l % (C / 4)) * 4;
    const int d   = blockIdx.x * NPB + grp;
    if (d >= NN) return;
    const int rs = row_start[d], re = row_start[d + 1];
    const float adv = ad_[d * 4 + hd];

    float den = 0.f;
    for (int i = rs; i < re; ++i) {
        int s = csr_src[i];
        den += __expf(lrelu02(as_[s * 4 + hd] + adv));
    }
    const float inv = 1.f / (den + 1e-16f);

    float4 acc = make_float4(0.f, 0.f, 0.f, 0.f);
    int s = (rs < re) ? csr_src[rs] : 0;
    for (int i = rs; i < re; ++i) {
        int sn = (i + 1 < re) ? csr_src[i + 1] : 0;
        float w = __expf(lrelu02(as_[s * 4 + hd] + adv)) * inv;
        float4 hv = *(const float4*)(h + (size_t)s * (4 * C) + hd * C + c4);
        acc.x = fmaf(w, hv.x, acc.x);
        acc.y = fmaf(w, hv.y, acc.y);
        acc.z = fmaf(w, hv.z, acc.z);
        acc.w = fmaf(w, hv.w, acc.w);
        s = sn;
    }
    // reduce over the 4 head groups (lane strides C/4, 2*C/4)
    #pragma unroll
    for (int off = C / 4; off < C; off <<= 1) {
        acc.x += __shfl_xor(acc.x, off);
        acc.y += __shfl_xor(acc.y, off);
        acc.z += __shfl_xor(acc.z, off);
        acc.w += __shfl_xor(acc.w, off);
    }
    if (hd == 0) {
        float4 o;
        o.x = fmaxf(fmaf(acc.x, 0.25f, bias[c4 + 0]), 0.f);
        o.y = fmaxf(fmaf(acc.y, 0.25f, bias[c4 + 1]), 0.f);
        o.z = fmaxf(fmaf(acc.z, 0.25f, bias[c4 + 2]), 0.f);
        o.w = fmaxf(fmaf(acc.w, 0.25f, bias[c4 + 3]), 0.f);
        *(float4*)(out + (size_t)d * C + c4) = o;
    }
}

// ---------------- link decoder ----------------------------------------------
__global__ void link_kernel(const int* __restrict__ lsrc, const int* __restrict__ ldst,
                            const float* __restrict__ z, float* __restrict__ out) {
    int e = blockIdx.x * blockDim.x + threadIdx.x;
    if (e >= NL) return;
    const float4* zs = (const float4*)(z + (size_t)lsrc[e] * 32);
    const float4* zd = (const float4*)(z + (size_t)ldst[e] * 32);
    float sum = 0.f;
    #pragma unroll
    for (int i = 0; i < 8; ++i) {
        float4 a = zs[i], b = zd[i];
        sum += a.x * b.x + a.y * b.y + a.z * b.z + a.w * b.w;
    }
    out[e] = sum;
}

extern "C" void kernel_launch(void* const* d_in, const int* in_sizes, int n_in,
                              void* d_out, int out_size, void* d_ws, size_t ws_size,
                              hipStream_t stream) {
    const float* x     = (const float*)d_in[0];
    const int*   ei    = (const int*)d_in[1];
    const int*   eli   = (const int*)d_in[2];
    const float* W0    = (const float*)d_in[3];
    const float* as0   = (const float*)d_in[4];
    const float* ad0   = (const float*)d_in[5];
    const float* b0    = (const float*)d_in[6];
    const float* W1    = (const float*)d_in[7];
    const float* as1   = (const float*)d_in[8];
    const float* ad1   = (const float*)d_in[9];
    const float* b1    = (const float*)d_in[10];
    const float* lin_w = (const float*)d_in[11];
    const float* lin_b = (const float*)d_in[12];
    const float* d1_w  = (const float*)d_in[13];
    const float* d1_b  = (const float*)d_in[14];
    const float* d2_w  = (const float*)d_in[15];
    const float* d2_b  = (const float*)d_in[16];
    const float* d3_w  = (const float*)d_in[17];
    const float* d3_b  = (const float*)d_in[18];
    const float* d4_w  = (const float*)d_in[19];
    const float* d4_b  = (const float*)d_in[20];

    const int* src = ei;            // edge_index[0]
    const int* dst = ei + NE;       // edge_index[1]
    const int* ls  = eli;
    const int* ld  = eli + NL;

    float* ws = (float*)d_ws;
    // layout (floats): h [N*256] | out0/out1 [N*64] | as [N*4] | ad [N*4] | CSR ints
    float* h_buf = ws;
    float* outb  = ws + (size_t)NN * 256;
    float* asb   = ws + (size_t)NN * 320;
    float* adb   = ws + (size_t)NN * 324;
    int*   ideg  = (int*)(ws + (size_t)NN * 328);   // [NN]
    int*   irow  = ideg + NN;                       // [NN+1]
    int*   icur  = irow + NN + 1;                   // [NN]
    int*   ibsum = icur + NN;                       // [512]
    int*   isrc  = ibsum + 512;                     // [NE]
    // decoder intermediates reuse the h region
    float* z  = h_buf;                       // [N,32]
    float* e1 = h_buf + (size_t)NN * 32;     // [N,32]
    float* e2 = h_buf + (size_t)NN * 64;     // [N,64]
    float* e3 = h_buf + (size_t)NN * 128;    // [N,96]

    float* link_out = (float*)d_out;
    float* expr_out = (float*)d_out + NL;

    const int GM = (NN + 63) / 64;           // 64-row tiles
    const int NB = (NN + 255) / 256;         // 391 scan blocks

    // ---------------- CSR build (dst-major), reused by both layers ----------
    hipMemsetAsync(ideg, 0, (size_t)NN * 4, stream);
    deg_hist<<<(NE + 255) / 256, 256, 0, stream>>>(dst, ideg);
    scan1<<<NB, 256, 0, stream>>>(ideg, irow, ibsum);
    scan2<<<1, 512, 0, stream>>>(ibsum, NB);
    scan3<<<NB, 256, 0, stream>>>(irow, icur, ibsum);
    csr_scatter<<<(NE + 255) / 256, 256, 0, stream>>>(src, dst, icur, isrc);

    // ---------------- Layer 0 (C=64 per head) ----------------
    gemm_tiled<64, 128, false, false><<<dim3(GM, 2), 256, 0, stream>>>(x, W0, nullptr, h_buf, NN, 256);
    calc_alpha<64><<<(NN * HEADS + 255) / 256, 256, 0, stream>>>(h_buf, as0, ad0, asb, adb);
    csr_agg<64><<<(NN + 3) / 4, 256, 0, stream>>>(irow, isrc, asb, adb, h_buf, b0, outb);

    // ---------------- Layer 1 (C=32 per head) ----------------
    gemm_tiled<64, 128, false, false><<<dim3(GM, 1), 256, 0, stream>>>(outb, W1, nullptr, h_buf, NN, 128);
    calc_alpha<32><<<(NN * HEADS + 255) / 256, 256, 0, stream>>>(h_buf, as1, ad1, asb, adb);
    csr_agg<32><<<(NN + 7) / 8, 256, 0, stream>>>(irow, isrc, asb, adb, h_buf, b1, outb);

    // ---------------- lin: z = out1 @ lin_w + lin_b ----------------
    gemm_rows<32, 256, 8, false, true><<<NN / 8, 256, 0, stream>>>(outb, lin_w, lin_b, z, NN, 32);

    // ---------------- link decoder ----------------
    link_kernel<<<(NL + 255) / 256, 256, 0, stream>>>(ls, ld, z, link_out);

    // ---------------- expression decoder ----------------
    gemm_rows<32, 256, 8, true, true><<<NN / 8, 256, 0, stream>>>(z, d1_w, d1_b, e1, NN, 32);
    gemm_tiled<32, 64,  true,  true><<<dim3(GM, 1), 256, 0, stream>>>(e1, d2_w, d2_b, e2, NN, 64);
    gemm_tiled<64, 64,  true,  true><<<dim3(GM, 2), 256, 0, stream>>>(e2, d3_w, d3_b, e3, NN, 96);
    gemm_tiled<96, 128, false, true><<<dim3(GM, 4), 256, 0, stream>>>(e3, d4_w, d4_b, expr_out, NN, 500);
}

// Round 5
// 1331.599 us; speedup vs baseline: 1.1630x; 1.0068x over previous
//
#include <hip/hip_runtime.h>

#define NN 100000
#define NE 800000
#define NL 200000
#define HEADS 4

// ---------------- small-N row GEMM body (ncols==32) -------------------------
template<int K, int TPB, int RPB, bool RELU, bool BIAS>
__device__ __forceinline__ void grow_body(const float* __restrict__ A, const float* __restrict__ B,
                                          const float* __restrict__ bias, float* __restrict__ C,
                                          int n_rows, int ncols) {
    __shared__ float As[RPB][K];
    const int row0 = blockIdx.x * RPB;
    for (int i = threadIdx.x; i < RPB * K; i += TPB) {
        int r = i / K, k = i % K;
        int gr = row0 + r;
        As[r][k] = (gr < n_rows) ? A[(size_t)gr * K + k] : 0.f;
    }
    __syncthreads();
    const int cpr = TPB / RPB;
    const int r   = threadIdx.x / cpr;
    const int j0  = threadIdx.x % cpr;
    const int gr  = row0 + r;
    if (gr >= n_rows) return;
    for (int j = j0; j < ncols; j += cpr) {
        float s = BIAS ? bias[j] : 0.f;
        #pragma unroll
        for (int k = 0; k < K; ++k) s += As[r][k] * B[k * ncols + j];
        if (RELU) s = fmaxf(s, 0.f);
        C[(size_t)gr * ncols + j] = s;
    }
}

extern "C" __global__ void __launch_bounds__(256) grow_lin(const float* A, const float* B,
                                                           const float* bias, float* C) {
    grow_body<32, 256, 8, false, true>(A, B, bias, C, NN, 32);
}
extern "C" __global__ void __launch_bounds__(256) grow_d1(const float* A, const float* B,
                                                          const float* bias, float* C) {
    grow_body<32, 256, 8, true, true>(A, B, bias, C, NN, 32);
}

// ---------------- 64x64-tile GEMM body (d2, d3) -----------------------------
template<int K, int BN, bool RELU, bool BIAS>
__device__ __forceinline__ void gemm64_body(const float* __restrict__ A, const float* __restrict__ B,
                                            const float* __restrict__ bias, float* __restrict__ C,
                                            int M, int N) {
    constexpr int BM = 64, BK = 32;
    constexpr int TN = BN / 16;
    __shared__ float As[BK][BM];
    __shared__ float Bs[BK][BN];
    const int tid  = threadIdx.x;
    const int row0 = blockIdx.x * BM;
    const int col0 = blockIdx.y * BN;
    const int ty   = tid >> 4;
    const int tx   = tid & 15;

    float acc[4][TN] = {};

    for (int k0 = 0; k0 < K; k0 += BK) {
        for (int i = tid * 4; i < BM * BK; i += 1024) {
            int r  = i >> 5;
            int kk = i & 31;
            int gr = row0 + r;
            float4 v = make_float4(0.f, 0.f, 0.f, 0.f);
            if (gr < M) v = *(const float4*)(A + (size_t)gr * K + k0 + kk);
            int sw = ((kk >> 2) & 3) << 3;
            As[kk + 0][r ^ sw] = v.x;
            As[kk + 1][r ^ sw] = v.y;
            As[kk + 2][r ^ sw] = v.z;
            As[kk + 3][r ^ sw] = v.w;
        }
        for (int i = tid * 4; i < BK * BN; i += 1024) {
            int kk = i / BN, c = i % BN;
            int gc = col0 + c;
            float4 v = make_float4(0.f, 0.f, 0.f, 0.f);
            if (gc < N) v = *(const float4*)(B + (size_t)(k0 + kk) * N + gc);
            *(float4*)&Bs[kk][c] = v;
        }
        __syncthreads();
        #pragma unroll
        for (int kk = 0; kk < BK; ++kk) {
            int sw = ((kk >> 2) & 3) << 3;
            float4 a = *(const float4*)&As[kk][(ty * 4) ^ sw];
            float av[4] = {a.x, a.y, a.z, a.w};
            float bv[TN];
            #pragma unroll
            for (int q = 0; q < TN / 4; ++q) {
                float4 b = *(const float4*)&Bs[kk][q * 64 + tx * 4];
                bv[q*4+0] = b.x; bv[q*4+1] = b.y; bv[q*4+2] = b.z; bv[q*4+3] = b.w;
            }
            #pragma unroll
            for (int i = 0; i < 4; ++i)
                #pragma unroll
                for (int j = 0; j < TN; ++j)
                    acc[i][j] = fmaf(av[i], bv[j], acc[i][j]);
        }
        __syncthreads();
    }

    #pragma unroll
    for (int i = 0; i < 4; ++i) {
        int gr = row0 + ty * 4 + i;
        if (gr >= M) continue;
        #pragma unroll
        for (int q = 0; q < TN / 4; ++q) {
            int gc = col0 + q * 64 + tx * 4;
            if (gc >= N) continue;
            float4 o = make_float4(acc[i][q*4], acc[i][q*4+1], acc[i][q*4+2], acc[i][q*4+3]);
            if (BIAS) { o.x += bias[gc]; o.y += bias[gc+1]; o.z += bias[gc+2]; o.w += bias[gc+3]; }
            if (RELU) { o.x = fmaxf(o.x,0.f); o.y = fmaxf(o.y,0.f); o.z = fmaxf(o.z,0.f); o.w = fmaxf(o.w,0.f); }
            *(float4*)(C + (size_t)gr * N + gc) = o;
        }
    }
}

extern "C" __global__ void __launch_bounds__(256, 4) g64_d2(const float* A, const float* B,
                                                            const float* bias, float* C) {
    gemm64_body<32, 64, true, true>(A, B, bias, C, NN, 64);
}
extern "C" __global__ void __launch_bounds__(256, 4) g64_d3(const float* A, const float* B,
                                                            const float* bias, float* C) {
    gemm64_body<64, 64, true, true>(A, B, bias, C, NN, 96);
}

// ---------------- 128x128-tile GEMM body (L0, L1, d4) -----------------------
// 256 threads; thread (ty=tid/16, tx=tid%16) owns an 8x8 register tile.
// A staged transposed with XOR swizzle: As[kk][r ^ (((kk>>2)&3)<<3)].
// 64 FMAs per 64B LDS read per thread-kstep -> VALU-bound.
template<int K, bool RELU, bool BIAS>
__device__ __forceinline__ void gemm128_body(const float* __restrict__ A, const float* __restrict__ B,
                                             const float* __restrict__ bias, float* __restrict__ C,
                                             int M, int N) {
    constexpr int BM = 128, BN = 128, BK = 32;
    __shared__ float As[BK][BM];
    __shared__ float Bs[BK][BN];
    const int tid  = threadIdx.x;
    const int row0 = blockIdx.x * BM;
    const int col0 = blockIdx.y * BN;
    const int ty   = tid >> 4;       // 0..15 -> rows ty*8 .. ty*8+7
    const int tx   = tid & 15;       // cols tx*8 .. tx*8+7

    float acc[8][8] = {};

    for (int k0 = 0; k0 < K; k0 += BK) {
        // stage A (BM*BK = 4096 floats): coalesced float4 loads, swizzled transposed stores
        #pragma unroll
        for (int i0 = 0; i0 < BM * BK; i0 += 1024) {
            int i  = i0 + tid * 4;
            int r  = i >> 5;
            int kk = i & 31;
            int gr = row0 + r;
            float4 v = make_float4(0.f, 0.f, 0.f, 0.f);
            if (gr < M) v = *(const float4*)(A + (size_t)gr * K + k0 + kk);
            int sw = ((kk >> 2) & 3) << 3;
            As[kk + 0][r ^ sw] = v.x;
            As[kk + 1][r ^ sw] = v.y;
            As[kk + 2][r ^ sw] = v.z;
            As[kk + 3][r ^ sw] = v.w;
        }
        // stage B (BK*BN = 4096 floats): coalesced float4
        #pragma unroll
        for (int i0 = 0; i0 < BK * BN; i0 += 1024) {
            int i  = i0 + tid * 4;
            int kk = i >> 7;          // /BN
            int c  = i & 127;         // %BN
            int gc = col0 + c;
            float4 v = make_float4(0.f, 0.f, 0.f, 0.f);
            if (gc < N) v = *(const float4*)(B + (size_t)(k0 + kk) * N + gc);
            *(float4*)&Bs[kk][c] = v;
        }
        __syncthreads();

        #pragma unroll
        for (int kk = 0; kk < BK; ++kk) {
            int sw = ((kk >> 2) & 3) << 3;
            float4 a0 = *(const float4*)&As[kk][(ty * 8) ^ sw];
            float4 a1 = *(const float4*)&As[kk][(ty * 8 + 4) ^ sw];
            float4 b0 = *(const float4*)&Bs[kk][tx * 8];
            float4 b1 = *(const float4*)&Bs[kk][tx * 8 + 4];
            float av[8] = {a0.x, a0.y, a0.z, a0.w, a1.x, a1.y, a1.z, a1.w};
            float bv[8] = {b0.x, b0.y, b0.z, b0.w, b1.x, b1.y, b1.z, b1.w};
            #pragma unroll
            for (int i = 0; i < 8; ++i)
                #pragma unroll
                for (int j = 0; j < 8; ++j)
                    acc[i][j] = fmaf(av[i], bv[j], acc[i][j]);
        }
        __syncthreads();
    }

    #pragma unroll
    for (int i = 0; i < 8; ++i) {
        int gr = row0 + ty * 8 + i;
        if (gr >= M) continue;
        #pragma unroll
        for (int q = 0; q < 2; ++q) {
            int gc = col0 + tx * 8 + q * 4;
            if (gc >= N) continue;
            float4 o = make_float4(acc[i][q*4], acc[i][q*4+1], acc[i][q*4+2], acc[i][q*4+3]);
            if (BIAS) { o.x += bias[gc]; o.y += bias[gc+1]; o.z += bias[gc+2]; o.w += bias[gc+3]; }
            if (RELU) { o.x = fmaxf(o.x,0.f); o.y = fmaxf(o.y,0.f); o.z = fmaxf(o.z,0.f); o.w = fmaxf(o.w,0.f); }
            *(float4*)(C + (size_t)gr * N + gc) = o;
        }
    }
}

extern "C" __global__ void __launch_bounds__(256) g128_l0(const float* A, const float* B, float* C) {
    gemm128_body<64, false, false>(A, B, nullptr, C, NN, 256);
}
extern "C" __global__ void __launch_bounds__(256) g128_l1(const float* A, const float* B, float* C) {
    gemm128_body<64, false, false>(A, B, nullptr, C, NN, 128);
}
extern "C" __global__ void __launch_bounds__(256) g128_d4(const float* A, const float* B,
                                                          const float* bias, float* C) {
    gemm128_body<96, false, true>(A, B, bias, C, NN, 500);
}

// ---------------- per-(node,head) attention logits --------------------------
template<int C>
__device__ __forceinline__ void alpha_body(const float* __restrict__ h, const float* __restrict__ a_src,
                                           const float* __restrict__ a_dst, float* __restrict__ as_out,
                                           float* __restrict__ ad_out) {
    int i = blockIdx.x * blockDim.x + threadIdx.x;   // n*HEADS + hd
    if (i >= NN * HEADS) return;
    int n = i / HEADS, hd = i % HEADS;
    const float* hp  = h + (size_t)n * HEADS * C + hd * C;
    const float* asp = a_src + hd * C;
    const float* adp = a_dst + hd * C;
    float s1 = 0.f, s2 = 0.f;
    #pragma unroll 8
    for (int c = 0; c < C; ++c) { float v = hp[c]; s1 += v * asp[c]; s2 += v * adp[c]; }
    as_out[i] = s1; ad_out[i] = s2;
}

extern "C" __global__ void alpha64(const float* h, const float* a_src, const float* a_dst,
                                   float* as_out, float* ad_out) {
    alpha_body<64>(h, a_src, a_dst, as_out, ad_out);
}
extern "C" __global__ void alpha32(const float* h, const float* a_src, const float* a_dst,
                                   float* as_out, float* ad_out) {
    alpha_body<32>(h, a_src, a_dst, as_out, ad_out);
}

__device__ __forceinline__ float lrelu02(float v) { return v > 0.f ? v : 0.2f * v; }

// ---------------- CSR construction (dst-major), built once per launch -------
extern "C" __global__ void deg_hist(const int* __restrict__ dst, int* __restrict__ deg) {
    int e = blockIdx.x * blockDim.x + threadIdx.x;
    if (e < NE) atomicAdd(&deg[dst[e]], 1);
}

extern "C" __global__ void scan1(const int* __restrict__ deg, int* __restrict__ rs, int* __restrict__ bsum) {
    __shared__ int sd[256];
    int i = blockIdx.x * 256 + threadIdx.x;
    int v = (i < NN) ? deg[i] : 0;
    sd[threadIdx.x] = v;
    __syncthreads();
    for (int off = 1; off < 256; off <<= 1) {
        int t = (threadIdx.x >= off) ? sd[threadIdx.x - off] : 0;
        __syncthreads();
        sd[threadIdx.x] += t;
        __syncthreads();
    }
    if (i < NN) rs[i] = sd[threadIdx.x] - v;          // block-local exclusive
    if (threadIdx.x == 255) bsum[blockIdx.x] = sd[255];
}

extern "C" __global__ void scan2(int* __restrict__ bsum, int n) {
    __shared__ int sd[512];
    int v = (threadIdx.x < n) ? bsum[threadIdx.x] : 0;
    sd[threadIdx.x] = v;
    __syncthreads();
    for (int off = 1; off < 512; off <<= 1) {
        int t = (threadIdx.x >= off) ? sd[threadIdx.x - off] : 0;
        __syncthreads();
        sd[threadIdx.x] += t;
        __syncthreads();
    }
    if (threadIdx.x < n) bsum[threadIdx.x] = sd[threadIdx.x] - v;
}

extern "C" __global__ void scan3(int* __restrict__ rs, int* __restrict__ cursor, const int* __restrict__ bsum) {
    int i = blockIdx.x * 256 + threadIdx.x;
    if (i < NN) {
        int v = rs[i] + bsum[blockIdx.x];
        rs[i] = v;
        cursor[i] = v;
    }
    if (i == 0) rs[NN] = NE;
}

extern "C" __global__ void csr_scatter(const int* __restrict__ src, const int* __restrict__ dst,
                                       int* __restrict__ cursor, int* __restrict__ csr_src) {
    int e = blockIdx.x * blockDim.x + threadIdx.x;
    if (e < NE) {
        int pos = atomicAdd(&cursor[dst[e]], 1);
        csr_src[pos] = src[e];
    }
}

// ---------------- fused per-node softmax + aggregation + finalize -----------
template<int C>
__device__ __forceinline__ void cagg_body(const int* __restrict__ row_start, const int* __restrict__ csr_src,
                                          const float* __restrict__ as_, const float* __restrict__ ad_,
                                          const float* __restrict__ h, const float* __restrict__ bias,
                                          float* __restrict__ out) {
    constexpr int NPB = 256 / C;          // nodes per block
    const int tid = threadIdx.x;
    const int grp = tid / C;
    const int l   = tid % C;
    const int hd  = l / (C / 4);
    const int c4  = (l % (C / 4)) * 4;
    const int d   = blockIdx.x * NPB + grp;
    if (d >= NN) return;
    const int rs = row_start[d], re = row_start[d + 1];
    const float adv = ad_[d * 4 + hd];

    float den = 0.f;
    for (int i = rs; i < re; ++i) {
        int s = csr_src[i];
        den += __expf(lrelu02(as_[s * 4 + hd] + adv));
    }
    const float inv = 1.f / (den + 1e-16f);

    float4 acc = make_float4(0.f, 0.f, 0.f, 0.f);
    int s = (rs < re) ? csr_src[rs] : 0;
    for (int i = rs; i < re; ++i) {
        int sn = (i + 1 < re) ? csr_src[i + 1] : 0;
        float w = __expf(lrelu02(as_[s * 4 + hd] + adv)) * inv;
        float4 hv = *(const float4*)(h + (size_t)s * (4 * C) + hd * C + c4);
        acc.x = fmaf(w, hv.x, acc.x);
        acc.y = fmaf(w, hv.y, acc.y);
        acc.z = fmaf(w, hv.z, acc.z);
        acc.w = fmaf(w, hv.w, acc.w);
        s = sn;
    }
    #pragma unroll
    for (int off = C / 4; off < C; off <<= 1) {
        acc.x += __shfl_xor(acc.x, off);
        acc.y += __shfl_xor(acc.y, off);
        acc.z += __shfl_xor(acc.z, off);
        acc.w += __shfl_xor(acc.w, off);
    }
    if (hd == 0) {
        float4 o;
        o.x = fmaxf(fmaf(acc.x, 0.25f, bias[c4 + 0]), 0.f);
        o.y = fmaxf(fmaf(acc.y, 0.25f, bias[c4 + 1]), 0.f);
        o.z = fmaxf(fmaf(acc.z, 0.25f, bias[c4 + 2]), 0.f);
        o.w = fmaxf(fmaf(acc.w, 0.25f, bias[c4 + 3]), 0.f);
        *(float4*)(out + (size_t)d * C + c4) = o;
    }
}

extern "C" __global__ void __launch_bounds__(256) cagg64(const int* row_start, const int* csr_src,
                                                         const float* as_, const float* ad_,
                                                         const float* h, const float* bias, float* out) {
    cagg_body<64>(row_start, csr_src, as_, ad_, h, bias, out);
}
extern "C" __global__ void __launch_bounds__(256) cagg32(const int* row_start, const int* csr_src,
                                                         const float* as_, const float* ad_,
                                                         const float* h, const float* bias, float* out) {
    cagg_body<32>(row_start, csr_src, as_, ad_, h, bias, out);
}

// ---------------- link decoder ----------------------------------------------
extern "C" __global__ void link_k(const int* __restrict__ lsrc, const int* __restrict__ ldst,
                                  const float* __restrict__ z, float* __restrict__ out) {
    int e = blockIdx.x * blockDim.x + threadIdx.x;
    if (e >= NL) return;
    const float4* zs = (const float4*)(z + (size_t)lsrc[e] * 32);
    const float4* zd = (const float4*)(z + (size_t)ldst[e] * 32);
    float sum = 0.f;
    #pragma unroll
    for (int i = 0; i < 8; ++i) {
        float4 a = zs[i], b = zd[i];
        sum += a.x * b.x + a.y * b.y + a.z * b.z + a.w * b.w;
    }
    out[e] = sum;
}

extern "C" void kernel_launch(void* const* d_in, const int* in_sizes, int n_in,
                              void* d_out, int out_size, void* d_ws, size_t ws_size,
                              hipStream_t stream) {
    const float* x     = (const float*)d_in[0];
    const int*   ei    = (const int*)d_in[1];
    const int*   eli   = (const int*)d_in[2];
    const float* W0    = (const float*)d_in[3];
    const float* as0   = (const float*)d_in[4];
    const float* ad0   = (const float*)d_in[5];
    const float* b0    = (const float*)d_in[6];
    const float* W1    = (const float*)d_in[7];
    const float* as1   = (const float*)d_in[8];
    const float* ad1   = (const float*)d_in[9];
    const float* b1    = (const float*)d_in[10];
    const float* lin_w = (const float*)d_in[11];
    const float* lin_b = (const float*)d_in[12];
    const float* d1_w  = (const float*)d_in[13];
    const float* d1_b  = (const float*)d_in[14];
    const float* d2_w  = (const float*)d_in[15];
    const float* d2_b  = (const float*)d_in[16];
    const float* d3_w  = (const float*)d_in[17];
    const float* d3_b  = (const float*)d_in[18];
    const float* d4_w  = (const float*)d_in[19];
    const float* d4_b  = (const float*)d_in[20];

    const int* src = ei;            // edge_index[0]
    const int* dst = ei + NE;       // edge_index[1]
    const int* ls  = eli;
    const int* ld  = eli + NL;

    float* ws = (float*)d_ws;
    // layout (floats): h [N*256] | out0/out1 [N*64] | as [N*4] | ad [N*4] | CSR ints
    float* h_buf = ws;
    float* outb  = ws + (size_t)NN * 256;
    float* asb   = ws + (size_t)NN * 320;
    float* adb   = ws + (size_t)NN * 324;
    int*   ideg  = (int*)(ws + (size_t)NN * 328);   // [NN]
    int*   irow  = ideg + NN;                       // [NN+1]
    int*   icur  = irow + NN + 1;                   // [NN]
    int*   ibsum = icur + NN;                       // [512]
    int*   isrc  = ibsum + 512;                     // [NE]
    // decoder intermediates reuse the h region
    float* z  = h_buf;                       // [N,32]
    float* e1 = h_buf + (size_t)NN * 32;     // [N,32]
    float* e2 = h_buf + (size_t)NN * 64;     // [N,64]
    float* e3 = h_buf + (size_t)NN * 128;    // [N,96]

    float* link_out = (float*)d_out;
    float* expr_out = (float*)d_out + NL;

    const int GM64  = (NN + 63) / 64;        // 1563
    const int GM128 = (NN + 127) / 128;      // 782
    const int NB    = (NN + 255) / 256;      // 391 scan blocks

    // ---------------- CSR build (dst-major), reused by both layers ----------
    hipMemsetAsync(ideg, 0, (size_t)NN * 4, stream);
    deg_hist<<<(NE + 255) / 256, 256, 0, stream>>>(dst, ideg);
    scan1<<<NB, 256, 0, stream>>>(ideg, irow, ibsum);
    scan2<<<1, 512, 0, stream>>>(ibsum, NB);
    scan3<<<NB, 256, 0, stream>>>(irow, icur, ibsum);
    csr_scatter<<<(NE + 255) / 256, 256, 0, stream>>>(src, dst, icur, isrc);

    // ---------------- Layer 0 (C=64 per head) ----------------
    g128_l0<<<dim3(GM128, 2), 256, 0, stream>>>(x, W0, h_buf);
    alpha64<<<(NN * HEADS + 255) / 256, 256, 0, stream>>>(h_buf, as0, ad0, asb, adb);
    cagg64<<<(NN + 3) / 4, 256, 0, stream>>>(irow, isrc, asb, adb, h_buf, b0, outb);

    // ---------------- Layer 1 (C=32 per head) ----------------
    g128_l1<<<dim3(GM128, 1), 256, 0, stream>>>(outb, W1, h_buf);
    alpha32<<<(NN * HEADS + 255) / 256, 256, 0, stream>>>(h_buf, as1, ad1, asb, adb);
    cagg32<<<(NN + 7) / 8, 256, 0, stream>>>(irow, isrc, asb, adb, h_buf, b1, outb);

    // ---------------- lin: z = out1 @ lin_w + lin_b ----------------
    grow_lin<<<NN / 8, 256, 0, stream>>>(outb, lin_w, lin_b, z);

    // ---------------- link decoder ----------------
    link_k<<<(NL + 255) / 256, 256, 0, stream>>>(ls, ld, z, link_out);

    // ---------------- expression decoder ----------------
    grow_d1<<<NN / 8, 256, 0, stream>>>(z, d1_w, d1_b, e1);
    g64_d2<<<dim3(GM64, 1), 256, 0, stream>>>(e1, d2_w, d2_b, e2);
    g64_d3<<<dim3(GM64, 2), 256, 0, stream>>>(e2, d3_w, d3_b, e3);
    g128_d4<<<dim3(GM128, 4), 256, 0, stream>>>(e3, d4_w, d4_b, expr_out);
}

// Round 6
// 1199.588 us; speedup vs baseline: 1.2910x; 1.1100x over previous
//
#include <hip/hip_runtime.h>

#define NN 100000
#define NE 800000
#define NL 200000
#define HEADS 4

// ---------------- small-N row GEMM body (ncols==32) -------------------------
template<int K, int TPB, int RPB, bool RELU, bool BIAS>
__device__ __forceinline__ void grow_body(const float* __restrict__ A, const float* __restrict__ B,
                                          const float* __restrict__ bias, float* __restrict__ C,
                                          int n_rows, int ncols) {
    __shared__ float As[RPB][K];
    const int row0 = blockIdx.x * RPB;
    for (int i = threadIdx.x; i < RPB * K; i += TPB) {
        int r = i / K, k = i % K;
        int gr = row0 + r;
        As[r][k] = (gr < n_rows) ? A[(size_t)gr * K + k] : 0.f;
    }
    __syncthreads();
    const int cpr = TPB / RPB;
    const int r   = threadIdx.x / cpr;
    const int j0  = threadIdx.x % cpr;
    const int gr  = row0 + r;
    if (gr >= n_rows) return;
    for (int j = j0; j < ncols; j += cpr) {
        float s = BIAS ? bias[j] : 0.f;
        #pragma unroll
        for (int k = 0; k < K; ++k) s += As[r][k] * B[k * ncols + j];
        if (RELU) s = fmaxf(s, 0.f);
        C[(size_t)gr * ncols + j] = s;
    }
}

extern "C" __global__ void __launch_bounds__(256) grow_lin(const float* A, const float* B,
                                                           const float* bias, float* C) {
    grow_body<32, 256, 8, false, true>(A, B, bias, C, NN, 32);
}
extern "C" __global__ void __launch_bounds__(256) grow_d1(const float* A, const float* B,
                                                          const float* bias, float* C) {
    grow_body<32, 256, 8, true, true>(A, B, bias, C, NN, 32);
}

// ---------------- 64x64-tile GEMM body (d2, d3) -----------------------------
template<int K, int BN, bool RELU, bool BIAS>
__device__ __forceinline__ void gemm64_body(const float* __restrict__ A, const float* __restrict__ B,
                                            const float* __restrict__ bias, float* __restrict__ C,
                                            int M, int N) {
    constexpr int BM = 64, BK = 32;
    constexpr int TN = BN / 16;
    __shared__ float As[BK][BM];
    __shared__ float Bs[BK][BN];
    const int tid  = threadIdx.x;
    const int row0 = blockIdx.x * BM;
    const int col0 = blockIdx.y * BN;
    const int ty   = tid >> 4;
    const int tx   = tid & 15;

    float acc[4][TN] = {};

    for (int k0 = 0; k0 < K; k0 += BK) {
        for (int i = tid * 4; i < BM * BK; i += 1024) {
            int r  = i >> 5;
            int kk = i & 31;
            int gr = row0 + r;
            float4 v = make_float4(0.f, 0.f, 0.f, 0.f);
            if (gr < M) v = *(const float4*)(A + (size_t)gr * K + k0 + kk);
            int sw = ((kk >> 2) & 3) << 3;
            As[kk + 0][r ^ sw] = v.x;
            As[kk + 1][r ^ sw] = v.y;
            As[kk + 2][r ^ sw] = v.z;
            As[kk + 3][r ^ sw] = v.w;
        }
        for (int i = tid * 4; i < BK * BN; i += 1024) {
            int kk = i / BN, c = i % BN;
            int gc = col0 + c;
            float4 v = make_float4(0.f, 0.f, 0.f, 0.f);
            if (gc < N) v = *(const float4*)(B + (size_t)(k0 + kk) * N + gc);
            *(float4*)&Bs[kk][c] = v;
        }
        __syncthreads();
        #pragma unroll
        for (int kk = 0; kk < BK; ++kk) {
            int sw = ((kk >> 2) & 3) << 3;
            float4 a = *(const float4*)&As[kk][(ty * 4) ^ sw];
            float av[4] = {a.x, a.y, a.z, a.w};
            float bv[TN];
            #pragma unroll
            for (int q = 0; q < TN / 4; ++q) {
                float4 b = *(const float4*)&Bs[kk][q * 64 + tx * 4];
                bv[q*4+0] = b.x; bv[q*4+1] = b.y; bv[q*4+2] = b.z; bv[q*4+3] = b.w;
            }
            #pragma unroll
            for (int i = 0; i < 4; ++i)
                #pragma unroll
                for (int j = 0; j < TN; ++j)
                    acc[i][j] = fmaf(av[i], bv[j], acc[i][j]);
        }
        __syncthreads();
    }

    #pragma unroll
    for (int i = 0; i < 4; ++i) {
        int gr = row0 + ty * 4 + i;
        if (gr >= M) continue;
        #pragma unroll
        for (int q = 0; q < TN / 4; ++q) {
            int gc = col0 + q * 64 + tx * 4;
            if (gc >= N) continue;
            float4 o = make_float4(acc[i][q*4], acc[i][q*4+1], acc[i][q*4+2], acc[i][q*4+3]);
            if (BIAS) { o.x += bias[gc]; o.y += bias[gc+1]; o.z += bias[gc+2]; o.w += bias[gc+3]; }
            if (RELU) { o.x = fmaxf(o.x,0.f); o.y = fmaxf(o.y,0.f); o.z = fmaxf(o.z,0.f); o.w = fmaxf(o.w,0.f); }
            *(float4*)(C + (size_t)gr * N + gc) = o;
        }
    }
}

extern "C" __global__ void __launch_bounds__(256, 4) g64_d2(const float* A, const float* B,
                                                            const float* bias, float* C) {
    gemm64_body<32, 64, true, true>(A, B, bias, C, NN, 64);
}
extern "C" __global__ void __launch_bounds__(256, 4) g64_d3(const float* A, const float* B,
                                                            const float* bias, float* C) {
    gemm64_body<64, 64, true, true>(A, B, bias, C, NN, 96);
}

// ---------------- 128x128-tile GEMM body (L0, L1, d4) -----------------------
template<int K, bool RELU, bool BIAS>
__device__ __forceinline__ void gemm128_body(const float* __restrict__ A, const float* __restrict__ B,
                                             const float* __restrict__ bias, float* __restrict__ C,
                                             int M, int N) {
    constexpr int BM = 128, BN = 128, BK = 32;
    __shared__ float As[BK][BM];
    __shared__ float Bs[BK][BN];
    const int tid  = threadIdx.x;
    const int row0 = blockIdx.x * BM;
    const int col0 = blockIdx.y * BN;
    const int ty   = tid >> 4;       // 0..15 -> rows ty*8 .. ty*8+7
    const int tx   = tid & 15;       // cols tx*8 .. tx*8+7

    float acc[8][8] = {};

    for (int k0 = 0; k0 < K; k0 += BK) {
        #pragma unroll
        for (int i0 = 0; i0 < BM * BK; i0 += 1024) {
            int i  = i0 + tid * 4;
            int r  = i >> 5;
            int kk = i & 31;
            int gr = row0 + r;
            float4 v = make_float4(0.f, 0.f, 0.f, 0.f);
            if (gr < M) v = *(const float4*)(A + (size_t)gr * K + k0 + kk);
            int sw = ((kk >> 2) & 3) << 3;
            As[kk + 0][r ^ sw] = v.x;
            As[kk + 1][r ^ sw] = v.y;
            As[kk + 2][r ^ sw] = v.z;
            As[kk + 3][r ^ sw] = v.w;
        }
        #pragma unroll
        for (int i0 = 0; i0 < BK * BN; i0 += 1024) {
            int i  = i0 + tid * 4;
            int kk = i >> 7;          // /BN
            int c  = i & 127;         // %BN
            int gc = col0 + c;
            float4 v = make_float4(0.f, 0.f, 0.f, 0.f);
            if (gc < N) v = *(const float4*)(B + (size_t)(k0 + kk) * N + gc);
            *(float4*)&Bs[kk][c] = v;
        }
        __syncthreads();

        #pragma unroll
        for (int kk = 0; kk < BK; ++kk) {
            int sw = ((kk >> 2) & 3) << 3;
            float4 a0 = *(const float4*)&As[kk][(ty * 8) ^ sw];
            float4 a1 = *(const float4*)&As[kk][(ty * 8 + 4) ^ sw];
            float4 b0 = *(const float4*)&Bs[kk][tx * 8];
            float4 b1 = *(const float4*)&Bs[kk][tx * 8 + 4];
            float av[8] = {a0.x, a0.y, a0.z, a0.w, a1.x, a1.y, a1.z, a1.w};
            float bv[8] = {b0.x, b0.y, b0.z, b0.w, b1.x, b1.y, b1.z, b1.w};
            #pragma unroll
            for (int i = 0; i < 8; ++i)
                #pragma unroll
                for (int j = 0; j < 8; ++j)
                    acc[i][j] = fmaf(av[i], bv[j], acc[i][j]);
        }
        __syncthreads();
    }

    #pragma unroll
    for (int i = 0; i < 8; ++i) {
        int gr = row0 + ty * 8 + i;
        if (gr >= M) continue;
        #pragma unroll
        for (int q = 0; q < 2; ++q) {
            int gc = col0 + tx * 8 + q * 4;
            if (gc >= N) continue;
            float4 o = make_float4(acc[i][q*4], acc[i][q*4+1], acc[i][q*4+2], acc[i][q*4+3]);
            if (BIAS) { o.x += bias[gc]; o.y += bias[gc+1]; o.z += bias[gc+2]; o.w += bias[gc+3]; }
            if (RELU) { o.x = fmaxf(o.x,0.f); o.y = fmaxf(o.y,0.f); o.z = fmaxf(o.z,0.f); o.w = fmaxf(o.w,0.f); }
            *(float4*)(C + (size_t)gr * N + gc) = o;
        }
    }
}

extern "C" __global__ void __launch_bounds__(256) g128_l0(const float* A, const float* B, float* C) {
    gemm128_body<64, false, false>(A, B, nullptr, C, NN, 256);
}
extern "C" __global__ void __launch_bounds__(256) g128_l1(const float* A, const float* B, float* C) {
    gemm128_body<64, false, false>(A, B, nullptr, C, NN, 128);
}
extern "C" __global__ void __launch_bounds__(256) g128_d4(const float* A, const float* B,
                                                          const float* bias, float* C) {
    gemm128_body<96, false, true>(A, B, bias, C, NN, 500);
}

// ---------------- attention logits: wave-per-node, coalesced ----------------
// C=64: lane l holds float4 of the 256-float row at offset l*4 (head hd=l/16).
// Flat a_src/a_dst index for lane l, elem j is exactly l*4+j. 16-lane shfl
// reduce -> lane (l%16)==0 writes as/ad[n*4+hd].
extern "C" __global__ void __launch_bounds__(256) alpha64(const float* __restrict__ h,
                                                          const float* __restrict__ a_src,
                                                          const float* __restrict__ a_dst,
                                                          float* __restrict__ as_out,
                                                          float* __restrict__ ad_out) {
    const int wid = threadIdx.x >> 6;
    const int l   = threadIdx.x & 63;
    const int n   = blockIdx.x * 4 + wid;
    if (n >= NN) return;
    float4 hv = *(const float4*)(h + (size_t)n * 256 + l * 4);
    float4 sv = *(const float4*)(a_src + l * 4);
    float4 dv = *(const float4*)(a_dst + l * 4);
    float s1 = hv.x * sv.x + hv.y * sv.y + hv.z * sv.z + hv.w * sv.w;
    float s2 = hv.x * dv.x + hv.y * dv.y + hv.z * dv.z + hv.w * dv.w;
    #pragma unroll
    for (int off = 1; off < 16; off <<= 1) {
        s1 += __shfl_xor(s1, off);
        s2 += __shfl_xor(s2, off);
    }
    if ((l & 15) == 0) {
        int hd = l >> 4;
        as_out[n * 4 + hd] = s1;
        ad_out[n * 4 + hd] = s2;
    }
}

// C=32: lane l holds float2 at offset l*2 of the 128-float row; head hd=l/16.
extern "C" __global__ void __launch_bounds__(256) alpha32(const float* __restrict__ h,
                                                          const float* __restrict__ a_src,
                                                          const float* __restrict__ a_dst,
                                                          float* __restrict__ as_out,
                                                          float* __restrict__ ad_out) {
    const int wid = threadIdx.x >> 6;
    const int l   = threadIdx.x & 63;
    const int n   = blockIdx.x * 4 + wid;
    if (n >= NN) return;
    float2 hv = *(const float2*)(h + (size_t)n * 128 + l * 2);
    float2 sv = *(const float2*)(a_src + l * 2);
    float2 dv = *(const float2*)(a_dst + l * 2);
    float s1 = hv.x * sv.x + hv.y * sv.y;
    float s2 = hv.x * dv.x + hv.y * dv.y;
    #pragma unroll
    for (int off = 1; off < 16; off <<= 1) {
        s1 += __shfl_xor(s1, off);
        s2 += __shfl_xor(s2, off);
    }
    if ((l & 15) == 0) {
        int hd = l >> 4;
        as_out[n * 4 + hd] = s1;
        ad_out[n * 4 + hd] = s2;
    }
}

__device__ __forceinline__ float lrelu02(float v) { return v > 0.f ? v : 0.2f * v; }

// ---------------- CSR construction (dst-major), built once per launch -------
extern "C" __global__ void deg_hist(const int* __restrict__ dst, int* __restrict__ deg) {
    int e = blockIdx.x * blockDim.x + threadIdx.x;
    if (e < NE) atomicAdd(&deg[dst[e]], 1);
}

extern "C" __global__ void scan1(const int* __restrict__ deg, int* __restrict__ rs, int* __restrict__ bsum) {
    __shared__ int sd[256];
    int i = blockIdx.x * 256 + threadIdx.x;
    int v = (i < NN) ? deg[i] : 0;
    sd[threadIdx.x] = v;
    __syncthreads();
    for (int off = 1; off < 256; off <<= 1) {
        int t = (threadIdx.x >= off) ? sd[threadIdx.x - off] : 0;
        __syncthreads();
        sd[threadIdx.x] += t;
        __syncthreads();
    }
    if (i < NN) rs[i] = sd[threadIdx.x] - v;          // block-local exclusive
    if (threadIdx.x == 255) bsum[blockIdx.x] = sd[255];
}

extern "C" __global__ void scan2(int* __restrict__ bsum, int n) {
    __shared__ int sd[512];
    int v = (threadIdx.x < n) ? bsum[threadIdx.x] : 0;
    sd[threadIdx.x] = v;
    __syncthreads();
    for (int off = 1; off < 512; off <<= 1) {
        int t = (threadIdx.x >= off) ? sd[threadIdx.x - off] : 0;
        __syncthreads();
        sd[threadIdx.x] += t;
        __syncthreads();
    }
    if (threadIdx.x < n) bsum[threadIdx.x] = sd[threadIdx.x] - v;
}

extern "C" __global__ void scan3(int* __restrict__ rs, int* __restrict__ cursor, const int* __restrict__ bsum) {
    int i = blockIdx.x * 256 + threadIdx.x;
    if (i < NN) {
        int v = rs[i] + bsum[blockIdx.x];
        rs[i] = v;
        cursor[i] = v;
    }
    if (i == 0) rs[NN] = NE;
}

extern "C" __global__ void csr_scatter(const int* __restrict__ src, const int* __restrict__ dst,
                                       int* __restrict__ cursor, int* __restrict__ csr_src) {
    int e = blockIdx.x * blockDim.x + threadIdx.x;
    if (e < NE) {
        int pos = atomicAdd(&cursor[dst[e]], 1);
        csr_src[pos] = src[e];
    }
}

// ---------------- fused SINGLE-PASS softmax aggregation ---------------------
// out = (sum_i exp(e_i) h_i) / (sum_i exp(e_i))  -- linearity of the numerator
// lets us skip the separate denominator pass. 2-edge software pipeline gives
// two independent load chains per iteration.
template<int C>
__device__ __forceinline__ void cagg_body(const int* __restrict__ row_start, const int* __restrict__ csr_src,
                                          const float* __restrict__ as_, const float* __restrict__ ad_,
                                          const float* __restrict__ h, const float* __restrict__ bias,
                                          float* __restrict__ out) {
    constexpr int NPB = 256 / C;          // nodes per block
    const int tid = threadIdx.x;
    const int grp = tid / C;
    const int l   = tid % C;
    const int hd  = l / (C / 4);
    const int c4  = (l % (C / 4)) * 4;
    const int d   = blockIdx.x * NPB + grp;
    if (d >= NN) return;
    const int rs = row_start[d], re = row_start[d + 1];
    const float adv = ad_[d * 4 + hd];

    float4 acc = make_float4(0.f, 0.f, 0.f, 0.f);
    float den = 0.f;
    int i = rs;
    for (; i + 2 <= re; i += 2) {
        int s0 = csr_src[i];
        int s1 = csr_src[i + 1];
        float a0 = as_[s0 * 4 + hd];
        float a1 = as_[s1 * 4 + hd];
        float4 h0 = *(const float4*)(h + (size_t)s0 * (4 * C) + hd * C + c4);
        float4 h1 = *(const float4*)(h + (size_t)s1 * (4 * C) + hd * C + c4);
        float w0 = __expf(lrelu02(a0 + adv));
        float w1 = __expf(lrelu02(a1 + adv));
        den += w0 + w1;
        acc.x = fmaf(w0, h0.x, fmaf(w1, h1.x, acc.x));
        acc.y = fmaf(w0, h0.y, fmaf(w1, h1.y, acc.y));
        acc.z = fmaf(w0, h0.z, fmaf(w1, h1.z, acc.z));
        acc.w = fmaf(w0, h0.w, fmaf(w1, h1.w, acc.w));
    }
    if (i < re) {
        int s0 = csr_src[i];
        float w0 = __expf(lrelu02(as_[s0 * 4 + hd] + adv));
        float4 h0 = *(const float4*)(h + (size_t)s0 * (4 * C) + hd * C + c4);
        den += w0;
        acc.x = fmaf(w0, h0.x, acc.x);
        acc.y = fmaf(w0, h0.y, acc.y);
        acc.z = fmaf(w0, h0.z, acc.z);
        acc.w = fmaf(w0, h0.w, acc.w);
    }
    // per-head normalize, then mean over heads via cross-group reduce
    const float inv = 1.f / (den + 1e-16f);
    acc.x *= inv; acc.y *= inv; acc.z *= inv; acc.w *= inv;
    #pragma unroll
    for (int off = C / 4; off < C; off <<= 1) {
        acc.x += __shfl_xor(acc.x, off);
        acc.y += __shfl_xor(acc.y, off);
        acc.z += __shfl_xor(acc.z, off);
        acc.w += __shfl_xor(acc.w, off);
    }
    if (hd == 0) {
        float4 o;
        o.x = fmaxf(fmaf(acc.x, 0.25f, bias[c4 + 0]), 0.f);
        o.y = fmaxf(fmaf(acc.y, 0.25f, bias[c4 + 1]), 0.f);
        o.z = fmaxf(fmaf(acc.z, 0.25f, bias[c4 + 2]), 0.f);
        o.w = fmaxf(fmaf(acc.w, 0.25f, bias[c4 + 3]), 0.f);
        *(float4*)(out + (size_t)d * C + c4) = o;
    }
}

extern "C" __global__ void __launch_bounds__(256) cagg64(const int* row_start, const int* csr_src,
                                                         const float* as_, const float* ad_,
                                                         const float* h, const float* bias, float* out) {
    cagg_body<64>(row_start, csr_src, as_, ad_, h, bias, out);
}
extern "C" __global__ void __launch_bounds__(256) cagg32(const int* row_start, const int* csr_src,
                                                         const float* as_, const float* ad_,
                                                         const float* h, const float* bias, float* out) {
    cagg_body<32>(row_start, csr_src, as_, ad_, h, bias, out);
}

// ---------------- link decoder ----------------------------------------------
extern "C" __global__ void link_k(const int* __restrict__ lsrc, const int* __restrict__ ldst,
                                  const float* __restrict__ z, float* __restrict__ out) {
    int e = blockIdx.x * blockDim.x + threadIdx.x;
    if (e >= NL) return;
    const float4* zs = (const float4*)(z + (size_t)lsrc[e] * 32);
    const float4* zd = (const float4*)(z + (size_t)ldst[e] * 32);
    float sum = 0.f;
    #pragma unroll
    for (int i = 0; i < 8; ++i) {
        float4 a = zs[i], b = zd[i];
        sum += a.x * b.x + a.y * b.y + a.z * b.z + a.w * b.w;
    }
    out[e] = sum;
}

extern "C" void kernel_launch(void* const* d_in, const int* in_sizes, int n_in,
                              void* d_out, int out_size, void* d_ws, size_t ws_size,
                              hipStream_t stream) {
    const float* x     = (const float*)d_in[0];
    const int*   ei    = (const int*)d_in[1];
    const int*   eli   = (const int*)d_in[2];
    const float* W0    = (const float*)d_in[3];
    const float* as0   = (const float*)d_in[4];
    const float* ad0   = (const float*)d_in[5];
    const float* b0    = (const float*)d_in[6];
    const float* W1    = (const float*)d_in[7];
    const float* as1   = (const float*)d_in[8];
    const float* ad1   = (const float*)d_in[9];
    const float* b1    = (const float*)d_in[10];
    const float* lin_w = (const float*)d_in[11];
    const float* lin_b = (const float*)d_in[12];
    const float* d1_w  = (const float*)d_in[13];
    const float* d1_b  = (const float*)d_in[14];
    const float* d2_w  = (const float*)d_in[15];
    const float* d2_b  = (const float*)d_in[16];
    const float* d3_w  = (const float*)d_in[17];
    const float* d3_b  = (const float*)d_in[18];
    const float* d4_w  = (const float*)d_in[19];
    const float* d4_b  = (const float*)d_in[20];

    const int* src = ei;            // edge_index[0]
    const int* dst = ei + NE;       // edge_index[1]
    const int* ls  = eli;
    const int* ld  = eli + NL;

    float* ws = (float*)d_ws;
    float* h_buf = ws;
    float* outb  = ws + (size_t)NN * 256;
    float* asb   = ws + (size_t)NN * 320;
    float* adb   = ws + (size_t)NN * 324;
    int*   ideg  = (int*)(ws + (size_t)NN * 328);   // [NN]
    int*   irow  = ideg + NN;                       // [NN+1]
    int*   icur  = irow + NN + 1;                   // [NN]
    int*   ibsum = icur + NN;                       // [512]
    int*   isrc  = ibsum + 512;                     // [NE]
    float* z  = h_buf;                       // [N,32]
    float* e1 = h_buf + (size_t)NN * 32;     // [N,32]
    float* e2 = h_buf + (size_t)NN * 64;     // [N,64]
    float* e3 = h_buf + (size_t)NN * 128;    // [N,96]

    float* link_out = (float*)d_out;
    float* expr_out = (float*)d_out + NL;

    const int GM64  = (NN + 63) / 64;        // 1563
    const int GM128 = (NN + 127) / 128;      // 782
    const int NB    = (NN + 255) / 256;      // 391 scan blocks

    // ---------------- CSR build (dst-major), reused by both layers ----------
    hipMemsetAsync(ideg, 0, (size_t)NN * 4, stream);
    deg_hist<<<(NE + 255) / 256, 256, 0, stream>>>(dst, ideg);
    scan1<<<NB, 256, 0, stream>>>(ideg, irow, ibsum);
    scan2<<<1, 512, 0, stream>>>(ibsum, NB);
    scan3<<<NB, 256, 0, stream>>>(irow, icur, ibsum);
    csr_scatter<<<(NE + 255) / 256, 256, 0, stream>>>(src, dst, icur, isrc);

    // ---------------- Layer 0 (C=64 per head) ----------------
    g128_l0<<<dim3(GM128, 2), 256, 0, stream>>>(x, W0, h_buf);
    alpha64<<<(NN + 3) / 4, 256, 0, stream>>>(h_buf, as0, ad0, asb, adb);
    cagg64<<<(NN + 3) / 4, 256, 0, stream>>>(irow, isrc, asb, adb, h_buf, b0, outb);

    // ---------------- Layer 1 (C=32 per head) ----------------
    g128_l1<<<dim3(GM128, 1), 256, 0, stream>>>(outb, W1, h_buf);
    alpha32<<<(NN + 3) / 4, 256, 0, stream>>>(h_buf, as1, ad1, asb, adb);
    cagg32<<<(NN + 7) / 8, 256, 0, stream>>>(irow, isrc, asb, adb, h_buf, b1, outb);

    // ---------------- lin: z = out1 @ lin_w + lin_b ----------------
    grow_lin<<<NN / 8, 256, 0, stream>>>(outb, lin_w, lin_b, z);

    // ---------------- link decoder ----------------
    link_k<<<(NL + 255) / 256, 256, 0, stream>>>(ls, ld, z, link_out);

    // ---------------- expression decoder ----------------
    grow_d1<<<NN / 8, 256, 0, stream>>>(z, d1_w, d1_b, e1);
    g64_d2<<<dim3(GM64, 1), 256, 0, stream>>>(e1, d2_w, d2_b, e2);
    g64_d3<<<dim3(GM64, 2), 256, 0, stream>>>(e2, d3_w, d3_b, e3);
    g128_d4<<<dim3(GM128, 4), 256, 0, stream>>>(e3, d4_w, d4_b, expr_out);
}